// Round 14
// baseline (228.041 us; speedup 1.0000x reference)
//
#include <hip/hip_runtime.h>
#include <hip/hip_bf16.h>
#include <math.h>

#define DIM 256
#define KCODES 8192
#define BN_TOTAL 32768
#define NSPLIT 2

// d_out flat f32 layout (reference return order)
#define OUT_IND 8388608
#define OUT_LOSS 8421376
#define OUT_CS 8421377
#define OUT_ES 8429569
#define OUT_TOTAL 10526721

// scratch-in-output offsets (f32 units)
#define ABUF_OFF 0           // x bf16 [32768][256] = 16 MB, dead after mfma
#define CBB_OFF 4194304      // cb bf16 [8192][256] (swizzled) = 4 MB, dead after mfma
#define PART_OFF OUT_ES      // partials float2[32768][8] = 2 MB, dead after pick

typedef unsigned short u16;
typedef unsigned int u32;
typedef __attribute__((ext_vector_type(8))) short bf16x8;
typedef __attribute__((ext_vector_type(4))) float f32x4;
typedef __attribute__((address_space(1))) const void gvoid_t;
typedef __attribute__((address_space(3))) void lvoid_t;

// ---------------- prep: x -> bf16 hi; cb -> bf16 hi (chunk-swizzled) + c2 ----
__global__ __launch_bounds__(256) void vq_prep(const float* __restrict__ x,
                                               const float* __restrict__ cb,
                                               u16* __restrict__ A,
                                               u16* __restrict__ B,
                                               float* __restrict__ c2,
                                               float* __restrict__ c2m) {
  int b = blockIdx.x;
  if (b < 4096) {
    int g = b * 256 + threadIdx.x;
    int row = g >> 5;
    int d0 = (g & 31) * 8;
    float4 v0 = *(const float4*)(x + (size_t)row * DIM + d0);
    float4 v1 = *(const float4*)(x + (size_t)row * DIM + d0 + 4);
    float vv[8] = {v0.x, v0.y, v0.z, v0.w, v1.x, v1.y, v1.z, v1.w};
    u16 h[8];
#pragma unroll
    for (int i = 0; i < 8; ++i) {
      __hip_bfloat16 bb = __float2bfloat16(vv[i]);
      h[i] = *reinterpret_cast<u16*>(&bb);
    }
    uint4 hv;
    hv.x = (u32)h[0] | ((u32)h[1] << 16); hv.y = (u32)h[2] | ((u32)h[3] << 16);
    hv.z = (u32)h[4] | ((u32)h[5] << 16); hv.w = (u32)h[6] | ((u32)h[7] << 16);
    *(uint4*)(A + (size_t)row * DIM + d0) = hv;
  } else {
    int g = (b - 4096) * 256 + threadIdx.x;
    int code = g >> 5;
    int l5 = g & 31;
    int d0 = l5 * 8;
    float4 v0 = *(const float4*)(cb + (size_t)code * DIM + d0);
    float4 v1 = *(const float4*)(cb + (size_t)code * DIM + d0 + 4);
    float vv[8] = {v0.x, v0.y, v0.z, v0.w, v1.x, v1.y, v1.z, v1.w};
    u16 h[8];
    float s = 0.0f;
#pragma unroll
    for (int i = 0; i < 8; ++i) {
      __hip_bfloat16 bb = __float2bfloat16(vv[i]);
      h[i] = *reinterpret_cast<u16*>(&bb);
      s += vv[i] * vv[i];
    }
    uint4 hv;
    hv.x = (u32)h[0] | ((u32)h[1] << 16); hv.y = (u32)h[2] | ((u32)h[3] << 16);
    hv.z = (u32)h[4] | ((u32)h[5] << 16); hv.w = (u32)h[6] | ((u32)h[7] << 16);
    // chunk swizzle: 16B chunk j of each 32-k group stored at j ^ ((code>>1)&3)
    int j = l5 & 3;
    int js = j ^ ((code >> 1) & 3);
    int d0s = ((l5 & ~3) | js) * 8;
    *(uint4*)(B + (size_t)code * DIM + d0s) = hv;
#pragma unroll
    for (int m = 1; m <= 16; m <<= 1) s += __shfl_xor(s, m, 64);
    if (l5 == 0) { c2[code] = s; c2m[code] = s - 256.0f; }
  }
}

// ---------------- main: counted-vmcnt pipelined MFMA + top-2 argmin --------
// r13 data path (BK=64, 2x2 wave split, b-in-regs, chunk swizzle) with the
// m201-style sync skeleton: ring-4 LDS buffers, 3-deep prefetch, raw
// s_barrier + counted s_waitcnt vmcnt(8) (never 0 in steady state) so staged
// loads stay in flight across barriers (T4), + setprio around MFMA (T5).
// Safety: RAW -- each wave's vmcnt(8) retires its own stage-cc (oldest-first,
// >=8 newer stage-loads outstanding) before barrier_B publishes the buffer.
// WAR -- stage(cc+3) writes the buffer last read at step cc-1; every wave's
// lgkmcnt(0) precedes its barrier_A arrival, so reads are drained first.
__global__ __launch_bounds__(256, 2)
void vq_mfma(const u16* __restrict__ XB, const u16* __restrict__ CBb,
             const float* __restrict__ c2m, float2* __restrict__ partials) {
  __shared__ __align__(16) u16 As[4][2][128][32];   // ring-4 x 16 KB = 64 KB
  const int t = threadIdx.x;
  const int wid = t >> 6;
  const int lane = t & 63;
  const int lhi = lane >> 4, llo = lane & 15;
  const int sl = lhi ^ ((llo >> 1) & 3);
  const int wm = wid & 1;    // code half of tile
  const int wn = wid >> 1;   // row half of tile
  const int rt = blockIdx.x & 255;
  const int s = blockIdx.x >> 8;           // 0..1
  const int row0 = rt * 128;
  const int code0base = s * (KCODES / NSPLIT);

  // preload x fragments: b[n][ks] = row (row0+wn*64+n*16+llo), k = ks*32+lhi*8
  bf16x8 b[4][8];
#pragma unroll
  for (int n = 0; n < 4; ++n) {
    const u16* bp = XB + (size_t)(row0 + wn * 64 + n * 16 + llo) * DIM + lhi * 8;
#pragma unroll
    for (int ks = 0; ks < 8; ++ks)
      b[n][ks] = *(const bf16x8*)(bp + ks * 32);
  }

  char* AsB = (char*)As;
  const int srow = lane >> 2;          // code within 16-code block
  const int scol = (lane & 3) << 3;    // stored-chunk u16 col within 32

  float v1[4], v2[4];
#pragma unroll
  for (int n = 0; n < 4; ++n) { v1[n] = INFINITY; v2[n] = INFINITY; }

  // stage chunk (sct, skb) -> ring buffer dbuf (4 loads/wave, 16 slices total)
  auto STAGE = [&](int sct, int skb, int dbuf) {
#pragma unroll
    for (int i = 0; i < 4; ++i) {
      const int p = wid * 4 + i;
      const int h = p >> 3;
      const int cblk = (p & 7) * 16;
      const u16* sp = CBb + (size_t)(code0base + sct * 128 + cblk + srow) * DIM +
                      skb * 64 + h * 32 + scol;
      char* dp = AsB + (dbuf << 14) + (p << 10);   // wave-uniform dest
      __builtin_amdgcn_global_load_lds((gvoid_t*)sp, (lvoid_t*)dp, 16, 0, 0);
    }
  };

  // epilogue: dist-256 = c2m - 2*dot; pack code into low 13 mantissa bits
  auto EPI = [&](int code0, f32x4 (&acc)[4][4]) {
#pragma unroll
    for (int m = 0; m < 4; ++m) {
      int cbase = code0 + wm * 64 + m * 16 + lhi * 4;
      float4 cv = *(const float4*)(c2m + cbase);
      float cvv[4] = {cv.x, cv.y, cv.z, cv.w};
#pragma unroll
      for (int n = 0; n < 4; ++n) {
#pragma unroll
        for (int r = 0; r < 4; ++r) {
          float d = fmaf(-2.0f, acc[m][n][r], cvv[r]);
          float key = __uint_as_float((__float_as_uint(d) & ~0x1FFFu) |
                                      (u32)(cbase + r));
          float lo = fminf(key, v1[n]);
          float hi = fmaxf(key, v1[n]);
          v1[n] = lo;
          v2[n] = fminf(v2[n], hi);
        }
      }
    }
  };

// one pipeline step: KB in [0,3] compile-time; reads ring buf KB, stages
// chunk CT4+KB+3 into ring buf (KB+3)&3.
#define VQ_STEP(CT4, KB, DOSTAGE, VMSTR)                                       \
  {                                                                            \
    asm volatile("s_waitcnt lgkmcnt(0)" ::: "memory");                         \
    __builtin_amdgcn_sched_barrier(0);                                         \
    __builtin_amdgcn_s_barrier(); /* A: everyone's prev reads drained */       \
    __builtin_amdgcn_sched_barrier(0);                                         \
    if (DOSTAGE) {                                                             \
      const int sc_ = (CT4) + (KB) + 3;                                        \
      STAGE(sc_ >> 2, ((KB) + 3) & 3, ((KB) + 3) & 3);                         \
    }                                                                          \
    __builtin_amdgcn_sched_barrier(0);                                         \
    asm volatile("s_waitcnt " VMSTR ::: "memory");                             \
    __builtin_amdgcn_sched_barrier(0);                                         \
    __builtin_amdgcn_s_barrier(); /* B: buffer KB published to all waves */    \
    __builtin_amdgcn_sched_barrier(0);                                         \
    const char* src_ = AsB + ((KB) << 14);                                     \
    _Pragma("unroll")                                                          \
    for (int ksub = 0; ksub < 2; ++ksub) {                                     \
      bf16x8 a_[4];                                                            \
      _Pragma("unroll")                                                        \
      for (int m = 0; m < 4; ++m)                                              \
        a_[m] = *(const bf16x8*)(src_ + (ksub << 13) +                         \
                                 ((wm * 64 + m * 16 + llo) << 6) + (sl << 4)); \
      __builtin_amdgcn_s_setprio(1);                                           \
      _Pragma("unroll")                                                        \
      for (int m = 0; m < 4; ++m)                                              \
        _Pragma("unroll")                                                      \
        for (int n = 0; n < 4; ++n)                                            \
          acc[m][n] = __builtin_amdgcn_mfma_f32_16x16x32_bf16(                 \
              a_[m], b[n][(KB) * 2 + ksub], acc[m][n], 0, 0, 0);               \
      __builtin_amdgcn_s_setprio(0);                                           \
    }                                                                          \
  }

  // prologue: 3 stages (12 loads) in flight
  STAGE(0, 0, 0);
  STAGE(0, 1, 1);
  STAGE(0, 2, 2);

#pragma unroll 1
  for (int ct = 0; ct < 31; ++ct) {
    const int ct4 = ct * 4;
    f32x4 acc[4][4];
#pragma unroll
    for (int m = 0; m < 4; ++m)
#pragma unroll
      for (int n = 0; n < 4; ++n) acc[m][n] = (f32x4){0.f, 0.f, 0.f, 0.f};
    VQ_STEP(ct4, 0, true, "vmcnt(8)")
    VQ_STEP(ct4, 1, true, "vmcnt(8)")
    VQ_STEP(ct4, 2, true, "vmcnt(8)")
    VQ_STEP(ct4, 3, true, "vmcnt(8)")
    EPI(code0base + ct * 128, acc);
  }
  {  // peeled tail ct = 31 (cc = 124..127): vmcnt ladder 8/8/4/0
    f32x4 acc[4][4];
#pragma unroll
    for (int m = 0; m < 4; ++m)
#pragma unroll
      for (int n = 0; n < 4; ++n) acc[m][n] = (f32x4){0.f, 0.f, 0.f, 0.f};
    VQ_STEP(124, 0, true, "vmcnt(8)")
    VQ_STEP(124, 1, false, "vmcnt(8)")
    VQ_STEP(124, 2, false, "vmcnt(4)")
    VQ_STEP(124, 3, false, "vmcnt(0)")
    EPI(code0base + 31 * 128, acc);
  }
#undef VQ_STEP

  // merge lhi pairs (0<->1, 2<->3); unique slot per (split, wm, lhi-pair):
  // 8 slots/row, each = top-2 of a disjoint 1024-code slice.
#pragma unroll
  for (int n = 0; n < 4; ++n) {
    float w1 = __shfl_xor(v1[n], 16, 64);
    float w2 = __shfl_xor(v2[n], 16, 64);
    float m1 = fminf(v1[n], w1);
    float m2 = fminf(fmaxf(v1[n], w1), fminf(v2[n], w2));
    if ((lhi & 1) == 0) {
      int row = row0 + wn * 64 + n * 16 + llo;
      int slot = s * 4 + wm * 2 + (lhi >> 1);
      partials[(size_t)row * 8 + slot] = make_float2(m1, m2);
    }
  }
}

// ---- pick: 16 cands -> top-4 -> exact rescore -> ind/out_ind/out_q/hist ----
__global__ __launch_bounds__(256)
void vq_pick(const float* __restrict__ x, const float* __restrict__ cb,
             const float* __restrict__ c2g, const float2* __restrict__ partials,
             int* __restrict__ ind, float* __restrict__ out_ind,
             float* __restrict__ out_q, int* __restrict__ cnt,
             float* __restrict__ loss_part) {
  __shared__ float lsm[4];
  int wid = threadIdx.x >> 6, lane = threadIdx.x & 63;
  int row = blockIdx.x * 4 + wid;
  float cv = INFINITY, cv2 = INFINITY;
  if (lane < 8) {
    float2 p = partials[(size_t)row * 8 + lane];
    cv = p.x; cv2 = p.y;
  }
  int cand[4];
#pragma unroll
  for (int rsel = 0; rsel < 4; ++rsel) {
    float bv = cv;
#pragma unroll
    for (int mask = 1; mask < 8; mask <<= 1)
      bv = fminf(bv, __shfl_xor(bv, mask, 64));
    bv = __shfl(bv, 0, 64);
    cand[rsel] = (int)(__float_as_uint(bv) & 8191u);
    if (cv == bv) { cv = cv2; cv2 = INFINITY; }
  }
  const float4 xv = *(const float4*)(x + (size_t)row * DIM + lane * 4);
  float4 q0 = *(const float4*)(cb + (size_t)cand[0] * DIM + lane * 4);
  float4 q1 = *(const float4*)(cb + (size_t)cand[1] * DIM + lane * 4);
  float4 q2 = *(const float4*)(cb + (size_t)cand[2] * DIM + lane * 4);
  float4 q3 = *(const float4*)(cb + (size_t)cand[3] * DIM + lane * 4);
  float d0 = xv.x * q0.x + xv.y * q0.y + xv.z * q0.z + xv.w * q0.w;
  float d1 = xv.x * q1.x + xv.y * q1.y + xv.z * q1.z + xv.w * q1.w;
  float d2 = xv.x * q2.x + xv.y * q2.y + xv.z * q2.z + xv.w * q2.w;
  float d3 = xv.x * q3.x + xv.y * q3.y + xv.z * q3.z + xv.w * q3.w;
  float x2 = xv.x * xv.x + xv.y * xv.y + xv.z * xv.z + xv.w * xv.w;
#pragma unroll
  for (int mask = 1; mask < 64; mask <<= 1) {
    d0 += __shfl_xor(d0, mask, 64);
    d1 += __shfl_xor(d1, mask, 64);
    d2 += __shfl_xor(d2, mask, 64);
    d3 += __shfl_xor(d3, mask, 64);
    x2 += __shfl_xor(x2, mask, 64);
  }
  float e0 = fmaf(-2.0f, d0, c2g[cand[0]]);
  float e1 = fmaf(-2.0f, d1, c2g[cand[1]]);
  float e2 = fmaf(-2.0f, d2, c2g[cand[2]]);
  float e3 = fmaf(-2.0f, d3, c2g[cand[3]]);
  float best = e0; int bk = cand[0];
  if (e1 < best || (e1 == best && cand[1] < bk)) { best = e1; bk = cand[1]; }
  if (e2 < best || (e2 == best && cand[2] < bk)) { best = e2; bk = cand[2]; }
  if (e3 < best || (e3 == best && cand[3] < bk)) { best = e3; bk = cand[3]; }
  float4 q = (bk == cand[1]) ? q1 : (bk == cand[2]) ? q2 : (bk == cand[3]) ? q3 : q0;
  *(float4*)(out_q + (size_t)row * DIM + lane * 4) = q;
  if (lane == 0) {
    ind[row] = bk;
    out_ind[row] = (float)bk;
    atomicAdd(cnt + bk, 1);
    lsm[wid] = x2 + best;   // == ||q - x||^2 (exact identity)
  }
  __syncthreads();
  if (threadIdx.x == 0)
    loss_part[blockIdx.x] = lsm[0] + lsm[1] + lsm[2] + lsm[3];
}

// ---- scan: exclusive scan cnt -> offs/woffs; out_cs; reduce loss ----
__global__ __launch_bounds__(1024)
void vq_scan(const int* __restrict__ cnt, int* __restrict__ offs,
             int* __restrict__ woffs, float* __restrict__ out_cs,
             const float* __restrict__ loss_part, float* __restrict__ out_loss) {
  __shared__ int ssum[1024];
  __shared__ float sls[1024];
  int tid = threadIdx.x;
  int c[8], loc[8];
  int s = 0;
#pragma unroll
  for (int j = 0; j < 8; ++j) {
    c[j] = cnt[tid * 8 + j];
    loc[j] = s;
    s += c[j];
  }
  ssum[tid] = s;
  float ls = 0.0f;
#pragma unroll
  for (int j = 0; j < 8; ++j) ls += loss_part[tid * 8 + j];
  sls[tid] = ls;
  __syncthreads();
  for (int off = 1; off < 1024; off <<= 1) {
    int v = (tid >= off) ? ssum[tid - off] : 0;
    __syncthreads();
    ssum[tid] += v;
    __syncthreads();
  }
  int base = (tid > 0) ? ssum[tid - 1] : 0;
#pragma unroll
  for (int j = 0; j < 8; ++j) {
    int o = base + loc[j];
    offs[tid * 8 + j] = o;
    woffs[tid * 8 + j] = o;
    out_cs[tid * 8 + j] = (float)c[j];
  }
  for (int off = 512; off >= 1; off >>= 1) {
    if (tid < off) sls[tid] += sls[tid + off];
    __syncthreads();
  }
  if (tid == 0) *out_loss = sls[0] * (1.0f / 8388608.0f);
}

// ---- scatter: build rowlist grouped by code ----
__global__ __launch_bounds__(256)
void vq_scatter(const int* __restrict__ ind, int* __restrict__ woffs,
                int* __restrict__ rowlist) {
  int row = blockIdx.x * 256 + threadIdx.x;
  int k = ind[row];
  int pos = atomicAdd(woffs + k, 1);
  rowlist[pos] = row;
}

// ---- esum: ONE BLOCK (4 waves) PER CODE; unroll-4 ILP; LDS cross-wave ----
__global__ __launch_bounds__(256)
void vq_esum(const float* __restrict__ x, const int* __restrict__ offs,
             const int* __restrict__ cnt, const int* __restrict__ rowlist,
             float* __restrict__ out_es) {
  __shared__ float4 sred[3][64];
  int k = blockIdx.x;
  int wid = threadIdx.x >> 6, lane = threadIdx.x & 63;
  int start = offs[k], n = cnt[k];
  const int* rl = rowlist + start;
  int jb = (n * wid) >> 2, je = (n * (wid + 1)) >> 2;
  float4 acc = {0.f, 0.f, 0.f, 0.f};
  int j = jb;
  for (; j + 4 <= je; j += 4) {
    int r0 = rl[j], r1 = rl[j + 1], r2 = rl[j + 2], r3 = rl[j + 3];
    float4 v0 = *(const float4*)(x + (size_t)r0 * DIM + lane * 4);
    float4 v1 = *(const float4*)(x + (size_t)r1 * DIM + lane * 4);
    float4 v2 = *(const float4*)(x + (size_t)r2 * DIM + lane * 4);
    float4 v3 = *(const float4*)(x + (size_t)r3 * DIM + lane * 4);
    acc.x += v0.x + v1.x + v2.x + v3.x;
    acc.y += v0.y + v1.y + v2.y + v3.y;
    acc.z += v0.z + v1.z + v2.z + v3.z;
    acc.w += v0.w + v1.w + v2.w + v3.w;
  }
  for (; j < je; ++j) {
    int r = rl[j];
    float4 v = *(const float4*)(x + (size_t)r * DIM + lane * 4);
    acc.x += v.x; acc.y += v.y; acc.z += v.z; acc.w += v.w;
  }
  if (wid > 0) sred[wid - 1][lane] = acc;
  __syncthreads();
  if (wid == 0) {
    float4 a1 = sred[0][lane], a2 = sred[1][lane], a3 = sred[2][lane];
    acc.x += a1.x + a2.x + a3.x;
    acc.y += a1.y + a2.y + a3.y;
    acc.z += a1.z + a2.z + a3.z;
    acc.w += a1.w + a2.w + a3.w;
    *(float4*)(out_es + (size_t)k * DIM + lane * 4) = acc;
  }
}

extern "C" void kernel_launch(void* const* d_in, const int* in_sizes, int n_in,
                              void* d_out, int out_size, void* d_ws,
                              size_t ws_size, hipStream_t stream) {
  const float* x = (const float*)d_in[0];
  const float* cb = (const float*)d_in[1];
  float* out = (float*)d_out;
  float* out_q = out;
  float* out_ind = out + OUT_IND;
  float* out_loss = out + OUT_LOSS;
  float* out_cs = out + OUT_CS;
  float* out_es = out + OUT_ES;

  // Scratch-in-output (same proven layout as rounds 7-13):
  u16* Abuf = (u16*)(out + ABUF_OFF);
  u16* CBb = (u16*)(out + CBB_OFF);
  float2* partials = (float2*)(out + PART_OFF);

  // ws layout (448 KB; >= 2.21 MB proven available in round 1)
  char* w = (char*)d_ws;
  int* cnt = (int*)w;                              // 32 KB [memset 0]
  int* offs = (int*)(w + (32 << 10));              // 32 KB
  int* woffs = (int*)(w + (64 << 10));             // 32 KB
  float* loss_part = (float*)(w + (96 << 10));     // 32 KB
  int* ind = (int*)(w + (128 << 10));              // 128 KB
  int* rowlist = (int*)(w + (256 << 10));          // 128 KB
  float* c2 = (float*)(w + (384 << 10));           // 32 KB
  float* c2m = (float*)(w + (416 << 10));          // 32 KB

  hipMemsetAsync(cnt, 0, KCODES * sizeof(int), stream);
  vq_prep<<<5120, 256, 0, stream>>>(x, cb, Abuf, CBb, c2, c2m);
  vq_mfma<<<256 * NSPLIT, 256, 0, stream>>>(Abuf, CBb, c2m, partials);
  vq_pick<<<BN_TOTAL / 4, 256, 0, stream>>>(x, cb, c2, partials, ind, out_ind,
                                            out_q, cnt, loss_part);
  vq_scan<<<1, 1024, 0, stream>>>(cnt, offs, woffs, out_cs, loss_part, out_loss);
  vq_scatter<<<BN_TOTAL / 256, 256, 0, stream>>>(ind, woffs, rowlist);
  vq_esum<<<KCODES, 256, 0, stream>>>(x, offs, cnt, rowlist, out_es);
}

// Round 15
// 189.613 us; speedup vs baseline: 1.2027x; 1.2027x over previous
//
#include <hip/hip_runtime.h>
#include <hip/hip_bf16.h>
#include <math.h>

#define DIM 256
#define KCODES 8192
#define BN_TOTAL 32768
#define NSPLIT 2

// d_out flat f32 layout (reference return order)
#define OUT_IND 8388608
#define OUT_LOSS 8421376
#define OUT_CS 8421377
#define OUT_ES 8429569
#define OUT_TOTAL 10526721

// scratch-in-output offsets (f32 units)
#define XI8_OFF 0            // x i8 [32768][256] = 8 MB, dead after mfma
#define CI8_OFF 4194304      // cb i8 [8192][256] (swizzled) = 2 MB, dead after mfma
#define PART_OFF OUT_ES      // partials float2[32768][16][2] = 8 MB (exact fit), dead after pick

typedef unsigned short u16;
typedef unsigned char u8;
typedef unsigned int u32;
typedef __attribute__((ext_vector_type(4))) int i32x4;
typedef __attribute__((address_space(1))) const void gvoid_t;
typedef __attribute__((address_space(3))) void lvoid_t;

#define QSCALE (127.0f / 6.0f)
#define NEG2S2 (-2.0f * (6.0f / 127.0f) * (6.0f / 127.0f))

// ---- prep: x -> i8 (linear); cb -> i8 (chunk-swizzled) + exact c2/c2m ----
__global__ __launch_bounds__(256) void vq_prep(const float* __restrict__ x,
                                               const float* __restrict__ cb,
                                               u8* __restrict__ Xi8,
                                               u8* __restrict__ Ci8,
                                               float* __restrict__ c2,
                                               float* __restrict__ c2m) {
  int b = blockIdx.x;
  bool isx = (b < 2048);
  int g = (isx ? b : (b - 2048)) * 256 + threadIdx.x;
  int row = g >> 4;            // x row or code
  int chunk = g & 15;          // 16-element (16B) chunk
  const float* src = (isx ? x : cb) + (size_t)row * DIM + chunk * 16;
  float vv[16];
#pragma unroll
  for (int q = 0; q < 4; ++q) {
    float4 v = *(const float4*)(src + q * 4);
    vv[q * 4 + 0] = v.x; vv[q * 4 + 1] = v.y;
    vv[q * 4 + 2] = v.z; vv[q * 4 + 3] = v.w;
  }
  u32 w[4];
  float s = 0.0f;
#pragma unroll
  for (int q = 0; q < 4; ++q) {
    u32 acc = 0;
#pragma unroll
    for (int e = 0; e < 4; ++e) {
      float v = vv[q * 4 + e];
      s += v * v;
      float vs = fminf(fmaxf(v * QSCALE, -127.0f), 127.0f);
      int iv = (int)rintf(vs);
      acc |= ((u32)(u8)(char)iv) << (8 * e);
    }
    w[q] = acc;
  }
  uint4 pk = {w[0], w[1], w[2], w[3]};
  if (isx) {
    *(uint4*)(Xi8 + (size_t)row * DIM + chunk * 16) = pk;
  } else {
    // swizzle: 16B chunk j of each 64B k-group stored at j ^ ((code>>1)&3)
    int kbg = chunk >> 2;
    int j = chunk & 3;
    int js = j ^ ((row >> 1) & 3);
    *(uint4*)(Ci8 + (size_t)row * DIM + kbg * 64 + js * 16) = pk;
#pragma unroll
    for (int m = 1; m <= 8; m <<= 1) s += __shfl_xor(s, m, 64);  // 16-lane grp
    if (chunk == 0) { c2[row] = s; c2m[row] = s - 256.0f; }
  }
}

// ---------------- main: i8 MFMA (K=64) + packed-key top-3 argmin ----------
// r13's proven 2-barrier skeleton; dtype -> i8 halves MFMA cycles AND LDS
// bytes. LDS [dbuf][128 codes][64B] = 16 KB; byte-geometry identical to r13
// (row stride 64B, 16B chunks) -> same conflict-free swizzle (verified r7).
// Each lane tracks top-3 of its own 512-code slice (s,wm,lhi) via med3 --
// no cross-lane merge; 16 slices/row, exact-f32 rescore of top-4-of-48.
__global__ __launch_bounds__(256, 2)
void vq_mfma(const u8* __restrict__ XB, const u8* __restrict__ CBb,
             const float* __restrict__ c2m, float2* __restrict__ partials) {
  __shared__ __align__(16) u8 As[2][128][64];   // 16 KB
  const int t = threadIdx.x;
  const int wid = t >> 6;
  const int lane = t & 63;
  const int lhi = lane >> 4, llo = lane & 15;
  const int sl = lhi ^ ((llo >> 1) & 3);
  const int wm = wid & 1;    // code half of tile
  const int wn = wid >> 1;   // row half of tile
  const int rt = blockIdx.x & 255;
  const int s = blockIdx.x >> 8;           // 0..1
  const int row0 = rt * 128;
  const int code0base = s * (KCODES / NSPLIT);

  // preload x fragments: b[n][kb] = 16 i8 at row (row0+wn*64+n*16+llo),
  // K = kb*64 + lhi*16
  i32x4 b[4][4];
#pragma unroll
  for (int n = 0; n < 4; ++n) {
    const u8* bp = XB + (size_t)(row0 + wn * 64 + n * 16 + llo) * DIM + lhi * 16;
#pragma unroll
    for (int kb = 0; kb < 4; ++kb)
      b[n][kb] = *(const i32x4*)(bp + kb * 64);
  }

  char* AsB = (char*)As;
  const int srow = lane >> 2;          // code within 16-code block
  const int scol = (lane & 3) << 4;    // byte col within code's 64B k-group

  float v1[4], v2[4], v3[4];
#pragma unroll
  for (int n = 0; n < 4; ++n) { v1[n] = INFINITY; v2[n] = INFINITY; v3[n] = INFINITY; }

  // stage (ct,kb) -> dbuf d: 8 KB = 8 slices of 1 KB; 2 gload_lds per wave
  auto STAGE = [&](int ct, int kb, int d) {
#pragma unroll
    for (int i = 0; i < 2; ++i) {
      const int p = wid * 2 + i;
      const int cblk = p * 16;
      const u8* sp = CBb + (size_t)(code0base + ct * 128 + cblk + srow) * DIM +
                     kb * 64 + scol;
      char* dp = AsB + (d << 13) + (p << 10);   // wave-uniform dest
      __builtin_amdgcn_global_load_lds((gvoid_t*)sp, (lvoid_t*)dp, 16, 0, 0);
    }
  };

  STAGE(0, 0, 0);

#pragma unroll 1
  for (int ct = 0; ct < 32; ++ct) {
    const int code0 = code0base + ct * 128;
    i32x4 acc[4][4];
#pragma unroll
    for (int m = 0; m < 4; ++m)
#pragma unroll
      for (int n = 0; n < 4; ++n) acc[m][n] = (i32x4){0, 0, 0, 0};

#pragma unroll
    for (int kb = 0; kb < 4; ++kb) {
      const int cc = ct * 4 + kb;
      if (cc < 127) {
        const int nct = (kb == 3) ? ct + 1 : ct;
        const int nkb = (kb == 3) ? 0 : kb + 1;
        STAGE(nct, nkb, (cc + 1) & 1);
      }
      __syncthreads();
      const char* src = AsB + ((cc & 1) << 13);
      i32x4 a[4];
#pragma unroll
      for (int m = 0; m < 4; ++m)
        a[m] = *(const i32x4*)(src + ((wm * 64 + m * 16 + llo) << 6) + (sl << 4));
#pragma unroll
      for (int m = 0; m < 4; ++m)
#pragma unroll
        for (int n = 0; n < 4; ++n)
          acc[m][n] = __builtin_amdgcn_mfma_i32_16x16x64_i8(a[m], b[n][kb],
                                                            acc[m][n], 0, 0, 0);
      if (kb == 3) {
        // dist-256 = c2m - 2*s^2*dot_i; pack code in low 13 mantissa bits;
        // running top-3 per lane (slice = this lane's 512 codes)
#pragma unroll
        for (int m = 0; m < 4; ++m) {
          int cbase = code0 + wm * 64 + m * 16 + lhi * 4;
          float4 cv = *(const float4*)(c2m + cbase);
          float cvv[4] = {cv.x, cv.y, cv.z, cv.w};
#pragma unroll
          for (int n = 0; n < 4; ++n) {
#pragma unroll
            for (int r = 0; r < 4; ++r) {
              float d = fmaf((float)acc[m][n][r], NEG2S2, cvv[r]);
              float key = __uint_as_float((__float_as_uint(d) & ~0x1FFFu) |
                                          (u32)(cbase + r));
              float ov1 = v1[n], ov2 = v2[n];
              v1[n] = fminf(key, ov1);
              v2[n] = __builtin_amdgcn_fmed3f(key, ov1, v2[n]);
              v3[n] = __builtin_amdgcn_fmed3f(key, ov2, v3[n]);
            }
          }
        }
      }
      __syncthreads();
    }
  }
  // write top-3 per (row, slice); slice slot = s*8 + wm*4 + lhi; every lane
  // writes a unique (row, slot) -- no merge, no race.
#pragma unroll
  for (int n = 0; n < 4; ++n) {
    int row = row0 + wn * 64 + n * 16 + llo;
    int slot = s * 8 + wm * 4 + lhi;
    size_t base = ((size_t)row * 16 + slot) * 2;
    partials[base] = make_float2(v1[n], v2[n]);
    partials[base + 1] = make_float2(v3[n], 0.0f);
  }
}

// ---- pick: 48 cands -> top-4 -> exact f32 rescore -> outputs ----
__global__ __launch_bounds__(256)
void vq_pick(const float* __restrict__ x, const float* __restrict__ cb,
             const float* __restrict__ c2g, const float2* __restrict__ partials,
             int* __restrict__ ind, float* __restrict__ out_ind,
             float* __restrict__ out_q, int* __restrict__ cnt,
             float* __restrict__ loss_part) {
  __shared__ float lsm[4];
  int wid = threadIdx.x >> 6, lane = threadIdx.x & 63;
  int row = blockIdx.x * 4 + wid;
  float cv = INFINITY, cv2 = INFINITY, cv3 = INFINITY;
  if (lane < 16) {
    size_t base = ((size_t)row * 16 + lane) * 2;
    float2 a = partials[base];
    float2 bb = partials[base + 1];
    cv = a.x; cv2 = a.y; cv3 = bb.x;
  }
  int cand[4];
#pragma unroll
  for (int rsel = 0; rsel < 4; ++rsel) {
    float bv = cv;
#pragma unroll
    for (int mask = 1; mask < 16; mask <<= 1)
      bv = fminf(bv, __shfl_xor(bv, mask, 64));
    bv = __shfl(bv, 0, 64);
    cand[rsel] = (int)(__float_as_uint(bv) & 8191u);
    if (cv == bv) { cv = cv2; cv2 = cv3; cv3 = INFINITY; }
  }
  const float4 xv = *(const float4*)(x + (size_t)row * DIM + lane * 4);
  float4 q0 = *(const float4*)(cb + (size_t)cand[0] * DIM + lane * 4);
  float4 q1 = *(const float4*)(cb + (size_t)cand[1] * DIM + lane * 4);
  float4 q2 = *(const float4*)(cb + (size_t)cand[2] * DIM + lane * 4);
  float4 q3 = *(const float4*)(cb + (size_t)cand[3] * DIM + lane * 4);
  float d0 = xv.x * q0.x + xv.y * q0.y + xv.z * q0.z + xv.w * q0.w;
  float d1 = xv.x * q1.x + xv.y * q1.y + xv.z * q1.z + xv.w * q1.w;
  float d2 = xv.x * q2.x + xv.y * q2.y + xv.z * q2.z + xv.w * q2.w;
  float d3 = xv.x * q3.x + xv.y * q3.y + xv.z * q3.z + xv.w * q3.w;
  float x2 = xv.x * xv.x + xv.y * xv.y + xv.z * xv.z + xv.w * xv.w;
#pragma unroll
  for (int mask = 1; mask < 64; mask <<= 1) {
    d0 += __shfl_xor(d0, mask, 64);
    d1 += __shfl_xor(d1, mask, 64);
    d2 += __shfl_xor(d2, mask, 64);
    d3 += __shfl_xor(d3, mask, 64);
    x2 += __shfl_xor(x2, mask, 64);
  }
  float e0 = fmaf(-2.0f, d0, c2g[cand[0]]);
  float e1 = fmaf(-2.0f, d1, c2g[cand[1]]);
  float e2 = fmaf(-2.0f, d2, c2g[cand[2]]);
  float e3 = fmaf(-2.0f, d3, c2g[cand[3]]);
  float best = e0; int bk = cand[0];
  if (e1 < best || (e1 == best && cand[1] < bk)) { best = e1; bk = cand[1]; }
  if (e2 < best || (e2 == best && cand[2] < bk)) { best = e2; bk = cand[2]; }
  if (e3 < best || (e3 == best && cand[3] < bk)) { best = e3; bk = cand[3]; }
  float4 q = (bk == cand[1]) ? q1 : (bk == cand[2]) ? q2 : (bk == cand[3]) ? q3 : q0;
  *(float4*)(out_q + (size_t)row * DIM + lane * 4) = q;
  if (lane == 0) {
    ind[row] = bk;
    out_ind[row] = (float)bk;
    atomicAdd(cnt + bk, 1);
    lsm[wid] = x2 + best;   // == ||q - x||^2 (exact identity)
  }
  __syncthreads();
  if (threadIdx.x == 0)
    loss_part[blockIdx.x] = lsm[0] + lsm[1] + lsm[2] + lsm[3];
}

// ---- scan: exclusive scan cnt -> offs/woffs; out_cs; reduce loss ----
__global__ __launch_bounds__(1024)
void vq_scan(const int* __restrict__ cnt, int* __restrict__ offs,
             int* __restrict__ woffs, float* __restrict__ out_cs,
             const float* __restrict__ loss_part, float* __restrict__ out_loss) {
  __shared__ int ssum[1024];
  __shared__ float sls[1024];
  int tid = threadIdx.x;
  int c[8], loc[8];
  int s = 0;
#pragma unroll
  for (int j = 0; j < 8; ++j) {
    c[j] = cnt[tid * 8 + j];
    loc[j] = s;
    s += c[j];
  }
  ssum[tid] = s;
  float ls = 0.0f;
#pragma unroll
  for (int j = 0; j < 8; ++j) ls += loss_part[tid * 8 + j];
  sls[tid] = ls;
  __syncthreads();
  for (int off = 1; off < 1024; off <<= 1) {
    int v = (tid >= off) ? ssum[tid - off] : 0;
    __syncthreads();
    ssum[tid] += v;
    __syncthreads();
  }
  int base = (tid > 0) ? ssum[tid - 1] : 0;
#pragma unroll
  for (int j = 0; j < 8; ++j) {
    int o = base + loc[j];
    offs[tid * 8 + j] = o;
    woffs[tid * 8 + j] = o;
    out_cs[tid * 8 + j] = (float)c[j];
  }
  for (int off = 512; off >= 1; off >>= 1) {
    if (tid < off) sls[tid] += sls[tid + off];
    __syncthreads();
  }
  if (tid == 0) *out_loss = sls[0] * (1.0f / 8388608.0f);
}

// ---- scatter: build rowlist grouped by code ----
__global__ __launch_bounds__(256)
void vq_scatter(const int* __restrict__ ind, int* __restrict__ woffs,
                int* __restrict__ rowlist) {
  int row = blockIdx.x * 256 + threadIdx.x;
  int k = ind[row];
  int pos = atomicAdd(woffs + k, 1);
  rowlist[pos] = row;
}

// ---- esum: ONE BLOCK (4 waves) PER CODE; unroll-4 ILP; LDS cross-wave ----
__global__ __launch_bounds__(256)
void vq_esum(const float* __restrict__ x, const int* __restrict__ offs,
             const int* __restrict__ cnt, const int* __restrict__ rowlist,
             float* __restrict__ out_es) {
  __shared__ float4 sred[3][64];
  int k = blockIdx.x;
  int wid = threadIdx.x >> 6, lane = threadIdx.x & 63;
  int start = offs[k], n = cnt[k];
  const int* rl = rowlist + start;
  int jb = (n * wid) >> 2, je = (n * (wid + 1)) >> 2;
  float4 acc = {0.f, 0.f, 0.f, 0.f};
  int j = jb;
  for (; j + 4 <= je; j += 4) {
    int r0 = rl[j], r1 = rl[j + 1], r2 = rl[j + 2], r3 = rl[j + 3];
    float4 v0 = *(const float4*)(x + (size_t)r0 * DIM + lane * 4);
    float4 v1 = *(const float4*)(x + (size_t)r1 * DIM + lane * 4);
    float4 v2 = *(const float4*)(x + (size_t)r2 * DIM + lane * 4);
    float4 v3 = *(const float4*)(x + (size_t)r3 * DIM + lane * 4);
    acc.x += v0.x + v1.x + v2.x + v3.x;
    acc.y += v0.y + v1.y + v2.y + v3.y;
    acc.z += v0.z + v1.z + v2.z + v3.z;
    acc.w += v0.w + v1.w + v2.w + v3.w;
  }
  for (; j < je; ++j) {
    int r = rl[j];
    float4 v = *(const float4*)(x + (size_t)r * DIM + lane * 4);
    acc.x += v.x; acc.y += v.y; acc.z += v.z; acc.w += v.w;
  }
  if (wid > 0) sred[wid - 1][lane] = acc;
  __syncthreads();
  if (wid == 0) {
    float4 a1 = sred[0][lane], a2 = sred[1][lane], a3 = sred[2][lane];
    acc.x += a1.x + a2.x + a3.x;
    acc.y += a1.y + a2.y + a3.y;
    acc.z += a1.z + a2.z + a3.z;
    acc.w += a1.w + a2.w + a3.w;
    *(float4*)(out_es + (size_t)k * DIM + lane * 4) = acc;
  }
}

extern "C" void kernel_launch(void* const* d_in, const int* in_sizes, int n_in,
                              void* d_out, int out_size, void* d_ws,
                              size_t ws_size, hipStream_t stream) {
  const float* x = (const float*)d_in[0];
  const float* cb = (const float*)d_in[1];
  float* out = (float*)d_out;
  float* out_q = out;
  float* out_ind = out + OUT_IND;
  float* out_loss = out + OUT_LOSS;
  float* out_cs = out + OUT_CS;
  float* out_es = out + OUT_ES;

  // Scratch-in-output:
  //  Xi8 = out[0..2M f32) 8MB, Ci8 = out[4194304..+0.5M) 2MB -- dead after
  //      mfma; vq_pick rewrites all of out_q afterwards.
  //  partials = out_es region (exact 8MB fit) -- dead after pick; vq_esum
  //      rewrites all of out_es afterwards.
  u8* Xi8 = (u8*)(out + XI8_OFF);
  u8* Ci8 = (u8*)(out + CI8_OFF);
  float2* partials = (float2*)(out + PART_OFF);

  // ws layout (448 KB; >= 2.21 MB proven available in round 1)
  char* w = (char*)d_ws;
  int* cnt = (int*)w;                              // 32 KB [memset 0]
  int* offs = (int*)(w + (32 << 10));              // 32 KB
  int* woffs = (int*)(w + (64 << 10));             // 32 KB
  float* loss_part = (float*)(w + (96 << 10));     // 32 KB
  int* ind = (int*)(w + (128 << 10));              // 128 KB
  int* rowlist = (int*)(w + (256 << 10));          // 128 KB
  float* c2 = (float*)(w + (384 << 10));           // 32 KB
  float* c2m = (float*)(w + (416 << 10));          // 32 KB

  hipMemsetAsync(cnt, 0, KCODES * sizeof(int), stream);
  vq_prep<<<2560, 256, 0, stream>>>(x, cb, Xi8, Ci8, c2, c2m);
  vq_mfma<<<256 * NSPLIT, 256, 0, stream>>>(Xi8, Ci8, c2m, partials);
  vq_pick<<<BN_TOTAL / 4, 256, 0, stream>>>(x, cb, c2, partials, ind, out_ind,
                                            out_q, cnt, loss_part);
  vq_scan<<<1, 1024, 0, stream>>>(cnt, offs, woffs, out_cs, loss_part, out_loss);
  vq_scatter<<<BN_TOTAL / 256, 256, 0, stream>>>(ind, woffs, rowlist);
  vq_esum<<<KCODES, 256, 0, stream>>>(x, offs, cnt, rowlist, out_es);
}

// Round 16
// 184.478 us; speedup vs baseline: 1.2361x; 1.0278x over previous
//
#include <hip/hip_runtime.h>
#include <hip/hip_bf16.h>
#include <math.h>

#define DIM 256
#define KCODES 8192
#define BN_TOTAL 32768

// d_out flat f32 layout (reference return order)
#define OUT_IND 8388608
#define OUT_LOSS 8421376
#define OUT_CS 8421377
#define OUT_ES 8429569
#define OUT_TOTAL 10526721

// scratch-in-output offsets (f32 units)
#define XI8_OFF 0            // x i8 [32768][256] = 8 MB, dead after mfma
#define CI8_OFF 4194304      // cb i8 [8192][256] (swizzled) = 2 MB, dead after mfma
#define PART_OFF OUT_ES      // partials int2[32768][16] = 4 MB, dead after pick

typedef unsigned short u16;
typedef unsigned char u8;
typedef unsigned int u32;
typedef __attribute__((ext_vector_type(4))) int i32x4;
typedef __attribute__((address_space(1))) const void gvoid_t;
typedef __attribute__((address_space(3))) void lvoid_t;

#define QSCALE (127.0f / 6.0f)
#define INV_2S2 (16129.0f / 72.0f)   // 1/(2*s^2), s = 6/127

// ---- prep: x -> i8 (linear); cb -> i8 (chunk-swizzled) + exact c2 + c2i ----
__global__ __launch_bounds__(256) void vq_prep(const float* __restrict__ x,
                                               const float* __restrict__ cb,
                                               u8* __restrict__ Xi8,
                                               u8* __restrict__ Ci8,
                                               float* __restrict__ c2,
                                               int* __restrict__ c2i) {
  int b = blockIdx.x;
  bool isx = (b < 2048);
  int g = (isx ? b : (b - 2048)) * 256 + threadIdx.x;
  int row = g >> 4;            // x row or code
  int chunk = g & 15;          // 16-element (16B) chunk
  const float* src = (isx ? x : cb) + (size_t)row * DIM + chunk * 16;
  float vv[16];
#pragma unroll
  for (int q = 0; q < 4; ++q) {
    float4 v = *(const float4*)(src + q * 4);
    vv[q * 4 + 0] = v.x; vv[q * 4 + 1] = v.y;
    vv[q * 4 + 2] = v.z; vv[q * 4 + 3] = v.w;
  }
  u32 w[4];
  float s = 0.0f;
#pragma unroll
  for (int q = 0; q < 4; ++q) {
    u32 acc = 0;
#pragma unroll
    for (int e = 0; e < 4; ++e) {
      float v = vv[q * 4 + e];
      s += v * v;
      float vs = fminf(fmaxf(v * QSCALE, -127.0f), 127.0f);
      int iv = (int)rintf(vs);
      acc |= ((u32)(u8)(char)iv) << (8 * e);
    }
    w[q] = acc;
  }
  uint4 pk = {w[0], w[1], w[2], w[3]};
  if (isx) {
    *(uint4*)(Xi8 + (size_t)row * DIM + chunk * 16) = pk;
  } else {
    // swizzle: 16B chunk j of each 64B k-group stored at j ^ ((code>>1)&3)
    int kbg = chunk >> 2;
    int j = chunk & 3;
    int js = j ^ ((row >> 1) & 3);
    *(uint4*)(Ci8 + (size_t)row * DIM + kbg * 64 + js * 16) = pk;
#pragma unroll
    for (int m = 1; m <= 8; m <<= 1) s += __shfl_xor(s, m, 64);  // 16-lane grp
    if (chunk == 0) {
      c2[row] = s;
      c2i[row] = (int)rintf((s - 256.0f) * INV_2S2);
    }
  }
}

// ---------------- main: i8 MFMA (K=64) + integer-key top-2 argmin ----------
// 64-row blocks, grid 1024 (rt 0..511 x s 0..1), 4 blocks/CU resident
// (launch_bounds(256,4); b[2][4]=32 VGPR + acc[4][2]=32 AGPR fit the cap).
// LDS/staging byte-identical to r15 (128 codes x 64B, chunk swizzle,
// conflict-free). Epilogue all-int: diff = c2i - dot; key = (diff<<13)+code;
// top-2 per lane slice (s,wm,lhi) = 16 slices of 512 codes per row.
__global__ __launch_bounds__(256, 4)
void vq_mfma(const u8* __restrict__ XB, const u8* __restrict__ CBb,
             const int* __restrict__ c2i, int2* __restrict__ partials) {
  __shared__ __align__(16) u8 As[2][128][64];   // 16 KB
  const int t = threadIdx.x;
  const int wid = t >> 6;
  const int lane = t & 63;
  const int lhi = lane >> 4, llo = lane & 15;
  const int sl = lhi ^ ((llo >> 1) & 3);
  const int wm = wid & 1;    // code half of ct-tile (64 codes)
  const int wn = wid >> 1;   // row half of block (32 rows)
  const int rt = blockIdx.x & 511;
  const int s = blockIdx.x >> 9;           // 0..1
  const int row0 = rt * 64;
  const int code0base = s * 4096;

  // preload x fragments: b[n][kb] = 16 i8 at row (row0+wn*32+n*16+llo),
  // K = kb*64 + lhi*16
  i32x4 b[2][4];
#pragma unroll
  for (int n = 0; n < 2; ++n) {
    const u8* bp = XB + (size_t)(row0 + wn * 32 + n * 16 + llo) * DIM + lhi * 16;
#pragma unroll
    for (int kb = 0; kb < 4; ++kb)
      b[n][kb] = *(const i32x4*)(bp + kb * 64);
  }

  char* AsB = (char*)As;
  const int srow = lane >> 2;          // code within 16-code block
  const int scol = (lane & 3) << 4;    // byte col within code's 64B k-group

  int v1[2], v2[2];
#pragma unroll
  for (int n = 0; n < 2; ++n) { v1[n] = 0x7FFFFFFF; v2[n] = 0x7FFFFFFF; }

  // stage (ct,kb) -> dbuf d: 8 KB = 8 slices of 1 KB; 2 gload_lds per wave
  auto STAGE = [&](int ct, int kb, int d) {
#pragma unroll
    for (int i = 0; i < 2; ++i) {
      const int p = wid * 2 + i;
      const int cblk = p * 16;
      const u8* sp = CBb + (size_t)(code0base + ct * 128 + cblk + srow) * DIM +
                     kb * 64 + scol;
      char* dp = AsB + (d << 13) + (p << 10);   // wave-uniform dest
      __builtin_amdgcn_global_load_lds((gvoid_t*)sp, (lvoid_t*)dp, 16, 0, 0);
    }
  };

  STAGE(0, 0, 0);

#pragma unroll 1
  for (int ct = 0; ct < 32; ++ct) {
    const int code0 = code0base + ct * 128;
    i32x4 acc[4][2];
#pragma unroll
    for (int m = 0; m < 4; ++m)
#pragma unroll
      for (int n = 0; n < 2; ++n) acc[m][n] = (i32x4){0, 0, 0, 0};

#pragma unroll
    for (int kb = 0; kb < 4; ++kb) {
      const int cc = ct * 4 + kb;
      if (cc < 127) {
        const int nct = (kb == 3) ? ct + 1 : ct;
        const int nkb = (kb == 3) ? 0 : kb + 1;
        STAGE(nct, nkb, (cc + 1) & 1);
      }
      __syncthreads();
      const char* src = AsB + ((cc & 1) << 13);
      i32x4 a[4];
#pragma unroll
      for (int m = 0; m < 4; ++m)
        a[m] = *(const i32x4*)(src + ((wm * 64 + m * 16 + llo) << 6) + (sl << 4));
#pragma unroll
      for (int m = 0; m < 4; ++m)
#pragma unroll
        for (int n = 0; n < 2; ++n)
          acc[m][n] = __builtin_amdgcn_mfma_i32_16x16x64_i8(a[m], b[n][kb],
                                                            acc[m][n], 0, 0, 0);
      if (kb == 3) {
        // int key = ((c2i - dot) << 13) + code; running top-2 per lane-slice
#pragma unroll
        for (int m = 0; m < 4; ++m) {
          int cbase = code0 + wm * 64 + m * 16 + lhi * 4;
          int4 cv = *(const int4*)(c2i + cbase);
          int cvv[4] = {cv.x, cv.y, cv.z, cv.w};
#pragma unroll
          for (int n = 0; n < 2; ++n) {
#pragma unroll
            for (int r = 0; r < 4; ++r) {
              int diff = cvv[r] - acc[m][n][r];
              int key = (int)(((u32)diff << 13) + (u32)(cbase + r));
              int ov1 = v1[n];
              v1[n] = min(key, ov1);
              v2[n] = min(v2[n], max(key, ov1));
            }
          }
        }
      }
      __syncthreads();
    }
  }
  // write top-2 per (row, slice); slot = s*8 + wm*4 + lhi; every lane writes
  // a unique (row, slot) -- no merge, no race.
#pragma unroll
  for (int n = 0; n < 2; ++n) {
    int row = row0 + wn * 32 + n * 16 + llo;
    int slot = s * 8 + wm * 4 + lhi;
    partials[(size_t)row * 16 + slot] = make_int2(v1[n], v2[n]);
  }
}

// ---- pick: 32 cands -> top-4 -> exact f32 rescore -> outputs ----
__global__ __launch_bounds__(256)
void vq_pick(const float* __restrict__ x, const float* __restrict__ cb,
             const float* __restrict__ c2g, const int2* __restrict__ partials,
             int* __restrict__ ind, float* __restrict__ out_ind,
             float* __restrict__ out_q, int* __restrict__ cnt,
             float* __restrict__ loss_part) {
  __shared__ float lsm[4];
  int wid = threadIdx.x >> 6, lane = threadIdx.x & 63;
  int row = blockIdx.x * 4 + wid;
  int cv = 0x7FFFFFFF, cv2 = 0x7FFFFFFF;
  if (lane < 16) {
    int2 p = partials[(size_t)row * 16 + lane];
    cv = p.x; cv2 = p.y;
  }
  int cand[4];
#pragma unroll
  for (int rsel = 0; rsel < 4; ++rsel) {
    int bv = cv;
#pragma unroll
    for (int mask = 1; mask < 16; mask <<= 1)
      bv = min(bv, __shfl_xor(bv, mask, 64));
    bv = __shfl(bv, 0, 64);
    cand[rsel] = bv & 8191;
    if (cv == bv) { cv = cv2; cv2 = 0x7FFFFFFF; }
  }
  const float4 xv = *(const float4*)(x + (size_t)row * DIM + lane * 4);
  float4 q0 = *(const float4*)(cb + (size_t)cand[0] * DIM + lane * 4);
  float4 q1 = *(const float4*)(cb + (size_t)cand[1] * DIM + lane * 4);
  float4 q2 = *(const float4*)(cb + (size_t)cand[2] * DIM + lane * 4);
  float4 q3 = *(const float4*)(cb + (size_t)cand[3] * DIM + lane * 4);
  float d0 = xv.x * q0.x + xv.y * q0.y + xv.z * q0.z + xv.w * q0.w;
  float d1 = xv.x * q1.x + xv.y * q1.y + xv.z * q1.z + xv.w * q1.w;
  float d2 = xv.x * q2.x + xv.y * q2.y + xv.z * q2.z + xv.w * q2.w;
  float d3 = xv.x * q3.x + xv.y * q3.y + xv.z * q3.z + xv.w * q3.w;
  float x2 = xv.x * xv.x + xv.y * xv.y + xv.z * xv.z + xv.w * xv.w;
#pragma unroll
  for (int mask = 1; mask < 64; mask <<= 1) {
    d0 += __shfl_xor(d0, mask, 64);
    d1 += __shfl_xor(d1, mask, 64);
    d2 += __shfl_xor(d2, mask, 64);
    d3 += __shfl_xor(d3, mask, 64);
    x2 += __shfl_xor(x2, mask, 64);
  }
  float e0 = fmaf(-2.0f, d0, c2g[cand[0]]);
  float e1 = fmaf(-2.0f, d1, c2g[cand[1]]);
  float e2 = fmaf(-2.0f, d2, c2g[cand[2]]);
  float e3 = fmaf(-2.0f, d3, c2g[cand[3]]);
  float best = e0; int bk = cand[0];
  if (e1 < best || (e1 == best && cand[1] < bk)) { best = e1; bk = cand[1]; }
  if (e2 < best || (e2 == best && cand[2] < bk)) { best = e2; bk = cand[2]; }
  if (e3 < best || (e3 == best && cand[3] < bk)) { best = e3; bk = cand[3]; }
  float4 q = (bk == cand[1]) ? q1 : (bk == cand[2]) ? q2 : (bk == cand[3]) ? q3 : q0;
  *(float4*)(out_q + (size_t)row * DIM + lane * 4) = q;
  if (lane == 0) {
    ind[row] = bk;
    out_ind[row] = (float)bk;
    atomicAdd(cnt + bk, 1);
    lsm[wid] = x2 + best;   // == ||q - x||^2 (exact identity)
  }
  __syncthreads();
  if (threadIdx.x == 0)
    loss_part[blockIdx.x] = lsm[0] + lsm[1] + lsm[2] + lsm[3];
}

// ---- scan: exclusive scan cnt -> offs/woffs; out_cs; reduce loss ----
__global__ __launch_bounds__(1024)
void vq_scan(const int* __restrict__ cnt, int* __restrict__ offs,
             int* __restrict__ woffs, float* __restrict__ out_cs,
             const float* __restrict__ loss_part, float* __restrict__ out_loss) {
  __shared__ int ssum[1024];
  __shared__ float sls[1024];
  int tid = threadIdx.x;
  int c[8], loc[8];
  int s = 0;
#pragma unroll
  for (int j = 0; j < 8; ++j) {
    c[j] = cnt[tid * 8 + j];
    loc[j] = s;
    s += c[j];
  }
  ssum[tid] = s;
  float ls = 0.0f;
#pragma unroll
  for (int j = 0; j < 8; ++j) ls += loss_part[tid * 8 + j];
  sls[tid] = ls;
  __syncthreads();
  for (int off = 1; off < 1024; off <<= 1) {
    int v = (tid >= off) ? ssum[tid - off] : 0;
    __syncthreads();
    ssum[tid] += v;
    __syncthreads();
  }
  int base = (tid > 0) ? ssum[tid - 1] : 0;
#pragma unroll
  for (int j = 0; j < 8; ++j) {
    int o = base + loc[j];
    offs[tid * 8 + j] = o;
    woffs[tid * 8 + j] = o;
    out_cs[tid * 8 + j] = (float)c[j];
  }
  for (int off = 512; off >= 1; off >>= 1) {
    if (tid < off) sls[tid] += sls[tid + off];
    __syncthreads();
  }
  if (tid == 0) *out_loss = sls[0] * (1.0f / 8388608.0f);
}

// ---- scatter: build rowlist grouped by code ----
__global__ __launch_bounds__(256)
void vq_scatter(const int* __restrict__ ind, int* __restrict__ woffs,
                int* __restrict__ rowlist) {
  int row = blockIdx.x * 256 + threadIdx.x;
  int k = ind[row];
  int pos = atomicAdd(woffs + k, 1);
  rowlist[pos] = row;
}

// ---- esum: ONE BLOCK (4 waves) PER CODE; unroll-4 ILP; LDS cross-wave ----
__global__ __launch_bounds__(256)
void vq_esum(const float* __restrict__ x, const int* __restrict__ offs,
             const int* __restrict__ cnt, const int* __restrict__ rowlist,
             float* __restrict__ out_es) {
  __shared__ float4 sred[3][64];
  int k = blockIdx.x;
  int wid = threadIdx.x >> 6, lane = threadIdx.x & 63;
  int start = offs[k], n = cnt[k];
  const int* rl = rowlist + start;
  int jb = (n * wid) >> 2, je = (n * (wid + 1)) >> 2;
  float4 acc = {0.f, 0.f, 0.f, 0.f};
  int j = jb;
  for (; j + 4 <= je; j += 4) {
    int r0 = rl[j], r1 = rl[j + 1], r2 = rl[j + 2], r3 = rl[j + 3];
    float4 v0 = *(const float4*)(x + (size_t)r0 * DIM + lane * 4);
    float4 v1 = *(const float4*)(x + (size_t)r1 * DIM + lane * 4);
    float4 v2 = *(const float4*)(x + (size_t)r2 * DIM + lane * 4);
    float4 v3 = *(const float4*)(x + (size_t)r3 * DIM + lane * 4);
    acc.x += v0.x + v1.x + v2.x + v3.x;
    acc.y += v0.y + v1.y + v2.y + v3.y;
    acc.z += v0.z + v1.z + v2.z + v3.z;
    acc.w += v0.w + v1.w + v2.w + v3.w;
  }
  for (; j < je; ++j) {
    int r = rl[j];
    float4 v = *(const float4*)(x + (size_t)r * DIM + lane * 4);
    acc.x += v.x; acc.y += v.y; acc.z += v.z; acc.w += v.w;
  }
  if (wid > 0) sred[wid - 1][lane] = acc;
  __syncthreads();
  if (wid == 0) {
    float4 a1 = sred[0][lane], a2 = sred[1][lane], a3 = sred[2][lane];
    acc.x += a1.x + a2.x + a3.x;
    acc.y += a1.y + a2.y + a3.y;
    acc.z += a1.z + a2.z + a3.z;
    acc.w += a1.w + a2.w + a3.w;
    *(float4*)(out_es + (size_t)k * DIM + lane * 4) = acc;
  }
}

extern "C" void kernel_launch(void* const* d_in, const int* in_sizes, int n_in,
                              void* d_out, int out_size, void* d_ws,
                              size_t ws_size, hipStream_t stream) {
  const float* x = (const float*)d_in[0];
  const float* cb = (const float*)d_in[1];
  float* out = (float*)d_out;
  float* out_q = out;
  float* out_ind = out + OUT_IND;
  float* out_loss = out + OUT_LOSS;
  float* out_cs = out + OUT_CS;
  float* out_es = out + OUT_ES;

  // Scratch-in-output:
  //  Xi8 = out[0..2M f32) 8MB, Ci8 = out[4194304..+0.5M) 2MB -- dead after
  //      mfma; vq_pick rewrites all of out_q afterwards.
  //  partials = out_es region (4MB of 8MB) -- dead after pick; vq_esum
  //      rewrites all of out_es afterwards.
  u8* Xi8 = (u8*)(out + XI8_OFF);
  u8* Ci8 = (u8*)(out + CI8_OFF);
  int2* partials = (int2*)(out + PART_OFF);

  // ws layout (448 KB; >= 2.21 MB proven available in round 1)
  char* w = (char*)d_ws;
  int* cnt = (int*)w;                              // 32 KB [memset 0]
  int* offs = (int*)(w + (32 << 10));              // 32 KB
  int* woffs = (int*)(w + (64 << 10));             // 32 KB
  float* loss_part = (float*)(w + (96 << 10));     // 32 KB
  int* ind = (int*)(w + (128 << 10));              // 128 KB
  int* rowlist = (int*)(w + (256 << 10));          // 128 KB
  float* c2 = (float*)(w + (384 << 10));           // 32 KB
  int* c2i = (int*)(w + (416 << 10));              // 32 KB

  hipMemsetAsync(cnt, 0, KCODES * sizeof(int), stream);
  vq_prep<<<2560, 256, 0, stream>>>(x, cb, Xi8, Ci8, c2, c2i);
  vq_mfma<<<1024, 256, 0, stream>>>(Xi8, Ci8, c2i, partials);
  vq_pick<<<BN_TOTAL / 4, 256, 0, stream>>>(x, cb, c2, partials, ind, out_ind,
                                            out_q, cnt, loss_part);
  vq_scan<<<1, 1024, 0, stream>>>(cnt, offs, woffs, out_cs, loss_part, out_loss);
  vq_scatter<<<BN_TOTAL / 256, 256, 0, stream>>>(ind, woffs, rowlist);
  vq_esum<<<KCODES, 256, 0, stream>>>(x, offs, cnt, rowlist, out_es);
}